// Round 16
// baseline (45.354 us; speedup 1.0000x reference)
//
#include <hip/hip_runtime.h>

#define TT 262144
#define BB 16
#define SS 65536      // TT/4 quads per batch
#define QPB 1024      // output quads per block = 256 threads x 4 consecutive
#define TILEQ 1056    // QPB + 32 halo quads
#define PX(j) ((j) + ((j) >> 2))      // padded physical quad index
#define LDSQ 1320     // PX(1055)+1 = 1319 -> 1320
#define NREP 3        // DIAGNOSTIC: repeat accumulate loop to surface counters

// ---------------------------------------------------------------------------
// prep_w: build combined filter W (validated rounds 10-15).
//   out[4u+p] = sum_i W[p][i] * x[4u-64+i],  W[p][i] = 4*C_p[126+p-i]
// ---------------------------------------------------------------------------
__global__ __launch_bounds__(256) void prep_w(const float* __restrict__ H,
                                              const float* __restrict__ G,
                                              float* __restrict__ W) {
    int t = blockIdx.x * 256 + threadIdx.x;   // 0..2303
    int e = t >> 2;
    int k = t & 3;
    bool valid = (e < 4 * 132);
    float acc = 0.f;
    if (valid) {
        int p = e / 132;
        int i = e % 132;
        int dd = 126 + p - i;                 // valid 0..124
        if (dd >= 0 && dd <= 124) {
            int j0 = (3 - p) & 3;
#pragma unroll
            for (int jj = 0; jj < 16; ++jj) {
                int j = j0 + 4 * jj;
                if (j <= 62) {
                    int a = 124 - j - dd;
                    if (a >= 0 && a <= 62) acc += H[k * 63 + a] * G[k * 63 + j];
                }
            }
        }
    }
    acc += __shfl_xor(acc, 1);
    acc += __shfl_xor(acc, 2);
    if (valid && k == 0) W[e] = 4.0f * acc;
}

// ---------------------------------------------------------------------------
// Fused PQMF — EXACT round-14 structure (27.45 us), accumulate loop repeated
// NREP times for counter visibility. Result identical each rep; the memory
// clobber forbids cross-rep CSE of ds_reads. Loop time = (t - t_r14)/2.
// Phase mapping (validated rounds 2/8-15): component p <- W4[33p + k].
// ---------------------------------------------------------------------------
__global__ __launch_bounds__(256) void pqmf_fused(const float* __restrict__ x,
                                                  const float* __restrict__ Wg,
                                                  const float* __restrict__ H,
                                                  const float* __restrict__ G,
                                                  float* __restrict__ out) {
    __shared__ float4 xs4[LDSQ];

    const int tid = threadIdx.x;
    const int b = blockIdx.y;
    const int Q0 = blockIdx.x * QPB;
    const float4* X4 = reinterpret_cast<const float4*>(x + (size_t)b * TT);

    // ---- stage x tile (zero-fill halo outside [0,SS)), padded layout ----
    const int gq0 = Q0 - 16;
#pragma unroll
    for (int it = 0; it < 5; ++it) {
        int j = tid + it * 256;
        if (j < TILEQ) {
            int gq = gq0 + j;
            xs4[PX(j)] = (gq >= 0 && gq < SS) ? X4[gq]
                                              : make_float4(0.f, 0.f, 0.f, 0.f);
        }
    }
    __syncthreads();

    // phys index of tile quad (4*tid + j) is 5*tid + j + (j>>2)
    const float4* xp = xs4 + 5 * tid;

    float4 a0 = make_float4(0.f, 0.f, 0.f, 0.f);
    float4 a1 = a0, a2 = a0, a3 = a0;

    const float4* W4 = reinterpret_cast<const float4*>(Wg);

// one tap k: shared W quads, applied to 4 accumulators with window quads
#define TAP(k, x0, x1, x2, x3)                                                 \
    {                                                                          \
        const float4 W0 = W4[(k)];            /* phase 0 -> .x */              \
        const float4 W1 = W4[33 + (k)];       /* phase 1 -> .y */              \
        const float4 W2 = W4[66 + (k)];       /* phase 2 -> .z */              \
        const float4 W3 = W4[99 + (k)];       /* phase 3 -> .w */              \
        a0.x = fmaf(W0.w, (x0).w, fmaf(W0.z, (x0).z, fmaf(W0.y, (x0).y, fmaf(W0.x, (x0).x, a0.x)))); \
        a0.y = fmaf(W1.w, (x0).w, fmaf(W1.z, (x0).z, fmaf(W1.y, (x0).y, fmaf(W1.x, (x0).x, a0.y)))); \
        a0.z = fmaf(W2.w, (x0).w, fmaf(W2.z, (x0).z, fmaf(W2.y, (x0).y, fmaf(W2.x, (x0).x, a0.z)))); \
        a0.w = fmaf(W3.w, (x0).w, fmaf(W3.z, (x0).z, fmaf(W3.y, (x0).y, fmaf(W3.x, (x0).x, a0.w)))); \
        a1.x = fmaf(W0.w, (x1).w, fmaf(W0.z, (x1).z, fmaf(W0.y, (x1).y, fmaf(W0.x, (x1).x, a1.x)))); \
        a1.y = fmaf(W1.w, (x1).w, fmaf(W1.z, (x1).z, fmaf(W1.y, (x1).y, fmaf(W1.x, (x1).x, a1.y)))); \
        a1.z = fmaf(W2.w, (x1).w, fmaf(W2.z, (x1).z, fmaf(W2.y, (x1).y, fmaf(W2.x, (x1).x, a1.z)))); \
        a1.w = fmaf(W3.w, (x1).w, fmaf(W3.z, (x1).z, fmaf(W3.y, (x1).y, fmaf(W3.x, (x1).x, a1.w)))); \
        a2.x = fmaf(W0.w, (x2).w, fmaf(W0.z, (x2).z, fmaf(W0.y, (x2).y, fmaf(W0.x, (x2).x, a2.x)))); \
        a2.y = fmaf(W1.w, (x2).w, fmaf(W1.z, (x2).z, fmaf(W1.y, (x2).y, fmaf(W1.x, (x2).x, a2.y)))); \
        a2.z = fmaf(W2.w, (x2).w, fmaf(W2.z, (x2).z, fmaf(W2.y, (x2).y, fmaf(W2.x, (x2).x, a2.z)))); \
        a2.w = fmaf(W3.w, (x2).w, fmaf(W3.z, (x2).z, fmaf(W3.y, (x2).y, fmaf(W3.x, (x2).x, a2.w)))); \
        a3.x = fmaf(W0.w, (x3).w, fmaf(W0.z, (x3).z, fmaf(W0.y, (x3).y, fmaf(W0.x, (x3).x, a3.x)))); \
        a3.y = fmaf(W1.w, (x3).w, fmaf(W1.z, (x3).z, fmaf(W1.y, (x3).y, fmaf(W1.x, (x3).x, a3.y)))); \
        a3.z = fmaf(W2.w, (x3).w, fmaf(W2.z, (x3).z, fmaf(W2.y, (x3).y, fmaf(W2.x, (x3).x, a3.z)))); \
        a3.w = fmaf(W3.w, (x3).w, fmaf(W3.z, (x3).z, fmaf(W3.y, (x3).y, fmaf(W3.x, (x3).x, a3.w)))); \
    }

#pragma unroll 1
    for (int rep = 0; rep < NREP; ++rep) {
        asm volatile("" ::: "memory");   // forbid cross-rep CSE of LDS reads
        a0 = make_float4(0.f, 0.f, 0.f, 0.f);
        a1 = a0; a2 = a0; a3 = a0;

        // window holds quads (4mm..4mm+3) at phys xq[0..3]; xq advances by 5
        float4 w0 = xp[0], w1 = xp[1], w2 = xp[2], w3 = xp[3];

#pragma unroll 1
        for (int mm = 0; mm < 8; ++mm) {
            const float4* xq = xp + 5 * mm;
            const int k0 = 4 * mm;
            float4 n0 = xq[5];               // quad 4mm+4
            float4 n1 = xq[6];               // quad 4mm+5
            float4 n2 = xq[7];               // quad 4mm+6
            float4 n3 = xq[8];               // quad 4mm+7
            TAP(k0 + 0, w0, w1, w2, w3)
            TAP(k0 + 1, w1, w2, w3, n0)
            TAP(k0 + 2, w2, w3, n0, n1)
            TAP(k0 + 3, w3, n0, n1, n2)
            w0 = n0; w1 = n1; w2 = n2; w3 = n3;
        }
        TAP(32, w0, w1, w2, w3)              // tail tap: quads 32..35
    }
#undef TAP

    float4* ob4 = reinterpret_cast<float4*>(out + (size_t)b * TT);
    const int t0 = tid * 4;
    const int u0 = Q0 + t0;
    if ((unsigned)(u0 - 16) < (unsigned)(SS - 32))     ob4[u0]     = a0;
    if ((unsigned)(u0 + 1 - 16) < (unsigned)(SS - 32)) ob4[u0 + 1] = a1;
    if ((unsigned)(u0 + 2 - 16) < (unsigned)(SS - 32)) ob4[u0 + 2] = a2;
    if ((unsigned)(u0 + 3 - 16) < (unsigned)(SS - 32)) ob4[u0 + 3] = a3;

    // ---- edge quads (exact two-stage), only first/last block per batch ----
    const bool edgeLo = (blockIdx.x == 0);
    const bool edgeHi = (blockIdx.x == gridDim.x - 1);
    if (edgeLo || edgeHi) {
        const int q_local = tid >> 4;    // 0..15
        const int s_idx = tid & 15;      // 0..15
        const int u = edgeLo ? q_local : (SS - 16 + q_local);
        const int s = u - 7 + s_idx;
        float c0 = 0.f, c1 = 0.f, c2 = 0.f, c3 = 0.f;
        if (s >= 0 && s < SS) {
            const float* xsf = reinterpret_cast<const float*>(xs4);
            // logical tile float ef = xi - 4*Q0 + 64; physical = ef + 4*(ef>>4)
            const int lbase = 4 * s - 31 - 4 * Q0 + 64;
            float s0 = 0.f, s1 = 0.f, s2 = 0.f, s3 = 0.f;
#pragma unroll
            for (int a = 0; a < 63; ++a) {
                int ef = lbase + a;
                float xv = xsf[ef + 4 * (ef >> 4)];
                s0 += xv * H[a];
                s1 += xv * H[63 + a];
                s2 += xv * H[126 + a];
                s3 += xv * H[189 + a];
            }
            const int d4 = 4 * (s - u);  // -28..32
            {
                int j = d4 + 31;         // p = 0 (j can be 63 at s=u+8)
                if (j <= 62) c0 = s0 * G[j] + s1 * G[63 + j] + s2 * G[126 + j] + s3 * G[189 + j];
            }
            {
                int j = d4 + 30;         // p = 1, j in [2,62]
                c1 = s0 * G[j] + s1 * G[63 + j] + s2 * G[126 + j] + s3 * G[189 + j];
            }
            {
                int j = d4 + 29;         // p = 2, j in [1,61]
                c2 = s0 * G[j] + s1 * G[63 + j] + s2 * G[126 + j] + s3 * G[189 + j];
            }
            {
                int j = d4 + 28;         // p = 3, j in [0,60]
                c3 = s0 * G[j] + s1 * G[63 + j] + s2 * G[126 + j] + s3 * G[189 + j];
            }
        }
#pragma unroll
        for (int m = 8; m >= 1; m >>= 1) {
            c0 += __shfl_xor(c0, m);
            c1 += __shfl_xor(c1, m);
            c2 += __shfl_xor(c2, m);
            c3 += __shfl_xor(c3, m);
        }
        if (s_idx == 0) {
            float4 v = make_float4(4.f * c0, 4.f * c1, 4.f * c2, 4.f * c3);
            ob4[u] = v;
        }
    }
}

extern "C" void kernel_launch(void* const* d_in, const int* in_sizes, int n_in,
                              void* d_out, int out_size, void* d_ws, size_t ws_size,
                              hipStream_t stream) {
    const float* x = (const float*)d_in[0];
    const float* H = (const float*)d_in[1];
    const float* G = (const float*)d_in[2];
    float* outp = (float*)d_out;
    float* W = (float*)d_ws;   // 4*132 floats = 2112 B

    hipLaunchKernelGGL(prep_w, dim3(9), dim3(256), 0, stream, H, G, W);
    hipLaunchKernelGGL(pqmf_fused, dim3(SS / QPB, BB), dim3(256), 0, stream,
                       x, W, H, G, outp);
}

// Round 17
// 31.189 us; speedup vs baseline: 1.4542x; 1.4542x over previous
//
#include <hip/hip_runtime.h>

#define TT 262144
#define BB 16
#define SS 65536      // TT/4 quads per batch
#define QPB 512       // output quads per tile
#define TILEQ 544     // QPB + 32 halo quads
#define NTHR 128      // threads per block (2 waves); 4 consecutive quads/thread
#define PX(j) ((j) + ((j) >> 2))      // padded physical quad index
#define LDSQ 680      // PX(543)=678 -> 680

// ---------------------------------------------------------------------------
// prep_w: build combined filter W (validated rounds 10-16).
//   out[4u+p] = sum_i W[p][i] * x[4u-64+i],  W[p][i] = 4*C_p[126+p-i]
// ---------------------------------------------------------------------------
__global__ __launch_bounds__(256) void prep_w(const float* __restrict__ H,
                                              const float* __restrict__ G,
                                              float* __restrict__ W) {
    int t = blockIdx.x * 256 + threadIdx.x;   // 0..2303
    int e = t >> 2;
    int k = t & 3;
    bool valid = (e < 4 * 132);
    float acc = 0.f;
    if (valid) {
        int p = e / 132;
        int i = e % 132;
        int dd = 126 + p - i;                 // valid 0..124
        if (dd >= 0 && dd <= 124) {
            int j0 = (3 - p) & 3;
#pragma unroll
            for (int jj = 0; jj < 16; ++jj) {
                int j = j0 + 4 * jj;
                if (j <= 62) {
                    int a = 124 - j - dd;
                    if (a >= 0 && a <= 62) acc += H[k * 63 + a] * G[k * 63 + j];
                }
            }
        }
    }
    acc += __shfl_xor(acc, 1);
    acc += __shfl_xor(acc, 2);
    if (valid && k == 0) W[e] = 4.0f * acc;
}

// one tap k: shared W quads applied to 4 accumulators with window quads
#define TAP(k, x0, x1, x2, x3)                                                 \
    {                                                                          \
        const float4 W0 = W4[(k)];            /* phase 0 -> .x */              \
        const float4 W1 = W4[33 + (k)];       /* phase 1 -> .y */              \
        const float4 W2 = W4[66 + (k)];       /* phase 2 -> .z */              \
        const float4 W3 = W4[99 + (k)];       /* phase 3 -> .w */              \
        a0.x = fmaf(W0.w, (x0).w, fmaf(W0.z, (x0).z, fmaf(W0.y, (x0).y, fmaf(W0.x, (x0).x, a0.x)))); \
        a0.y = fmaf(W1.w, (x0).w, fmaf(W1.z, (x0).z, fmaf(W1.y, (x0).y, fmaf(W1.x, (x0).x, a0.y)))); \
        a0.z = fmaf(W2.w, (x0).w, fmaf(W2.z, (x0).z, fmaf(W2.y, (x0).y, fmaf(W2.x, (x0).x, a0.z)))); \
        a0.w = fmaf(W3.w, (x0).w, fmaf(W3.z, (x0).z, fmaf(W3.y, (x0).y, fmaf(W3.x, (x0).x, a0.w)))); \
        a1.x = fmaf(W0.w, (x1).w, fmaf(W0.z, (x1).z, fmaf(W0.y, (x1).y, fmaf(W0.x, (x1).x, a1.x)))); \
        a1.y = fmaf(W1.w, (x1).w, fmaf(W1.z, (x1).z, fmaf(W1.y, (x1).y, fmaf(W1.x, (x1).x, a1.y)))); \
        a1.z = fmaf(W2.w, (x1).w, fmaf(W2.z, (x1).z, fmaf(W2.y, (x1).y, fmaf(W2.x, (x1).x, a1.z)))); \
        a1.w = fmaf(W3.w, (x1).w, fmaf(W3.z, (x1).z, fmaf(W3.y, (x1).y, fmaf(W3.x, (x1).x, a1.w)))); \
        a2.x = fmaf(W0.w, (x2).w, fmaf(W0.z, (x2).z, fmaf(W0.y, (x2).y, fmaf(W0.x, (x2).x, a2.x)))); \
        a2.y = fmaf(W1.w, (x2).w, fmaf(W1.z, (x2).z, fmaf(W1.y, (x2).y, fmaf(W1.x, (x2).x, a2.y)))); \
        a2.z = fmaf(W2.w, (x2).w, fmaf(W2.z, (x2).z, fmaf(W2.y, (x2).y, fmaf(W2.x, (x2).x, a2.z)))); \
        a2.w = fmaf(W3.w, (x2).w, fmaf(W3.z, (x2).z, fmaf(W3.y, (x2).y, fmaf(W3.x, (x2).x, a2.w)))); \
        a3.x = fmaf(W0.w, (x3).w, fmaf(W0.z, (x3).z, fmaf(W0.y, (x3).y, fmaf(W0.x, (x3).x, a3.x)))); \
        a3.y = fmaf(W1.w, (x3).w, fmaf(W1.z, (x3).z, fmaf(W1.y, (x3).y, fmaf(W1.x, (x3).x, a3.y)))); \
        a3.z = fmaf(W2.w, (x3).w, fmaf(W2.z, (x3).z, fmaf(W2.y, (x3).y, fmaf(W2.x, (x3).x, a3.z)))); \
        a3.w = fmaf(W3.w, (x3).w, fmaf(W3.z, (x3).z, fmaf(W3.y, (x3).y, fmaf(W3.x, (x3).x, a3.w)))); \
    }

// compute one 512-quad tile from a staged LDS buffer (r14-validated window)
__device__ __forceinline__ void compute_tile(const float4* __restrict__ xsb,
                                             const float4* __restrict__ W4,
                                             float4* __restrict__ ob4,
                                             int Q0, int tid) {
    const float4* xp = xsb + 5 * tid;    // PX(4*tid) = 5*tid
    float4 a0 = make_float4(0.f, 0.f, 0.f, 0.f);
    float4 a1 = a0, a2 = a0, a3 = a0;

    float4 w0 = xp[0], w1 = xp[1], w2 = xp[2], w3 = xp[3];
#pragma unroll 1
    for (int mm = 0; mm < 8; ++mm) {
        const float4* xq = xp + 5 * mm;
        const int k0 = 4 * mm;
        float4 n0 = xq[5];
        float4 n1 = xq[6];
        float4 n2 = xq[7];
        float4 n3 = xq[8];
        TAP(k0 + 0, w0, w1, w2, w3)
        TAP(k0 + 1, w1, w2, w3, n0)
        TAP(k0 + 2, w2, w3, n0, n1)
        TAP(k0 + 3, w3, n0, n1, n2)
        w0 = n0; w1 = n1; w2 = n2; w3 = n3;
    }
    TAP(32, w0, w1, w2, w3)              // tail tap: quads 32..35

    const int u0 = Q0 + 4 * tid;
    if ((unsigned)(u0 - 16) < (unsigned)(SS - 32))     ob4[u0]     = a0;
    if ((unsigned)(u0 + 1 - 16) < (unsigned)(SS - 32)) ob4[u0 + 1] = a1;
    if ((unsigned)(u0 + 2 - 16) < (unsigned)(SS - 32)) ob4[u0 + 2] = a2;
    if ((unsigned)(u0 + 3 - 16) < (unsigned)(SS - 32)) ob4[u0 + 3] = a3;
}

// 16 edge quads starting at uBase via exact two-stage path, from staged tile
__device__ __forceinline__ void edge16(const float* __restrict__ xsf, int Q0,
                                       const float* __restrict__ H,
                                       const float* __restrict__ G,
                                       float4* __restrict__ ob4,
                                       int uBase, int tid) {
#pragma unroll 1
    for (int half = 0; half < 2; ++half) {
        const int q_local = (tid >> 4) + 8 * half;   // 0..15 over 2 halves
        const int s_idx = tid & 15;
        const int u = uBase + q_local;
        const int s = u - 7 + s_idx;
        float c0 = 0.f, c1 = 0.f, c2 = 0.f, c3 = 0.f;
        if (s >= 0 && s < SS) {
            const int lbase = 4 * s - 31 - 4 * Q0 + 64;
            float s0 = 0.f, s1 = 0.f, s2 = 0.f, s3 = 0.f;
#pragma unroll
            for (int a = 0; a < 63; ++a) {
                int ef = lbase + a;                  // logical tile float
                float xv = xsf[ef + 4 * (ef >> 4)]; // padded physical
                s0 += xv * H[a];
                s1 += xv * H[63 + a];
                s2 += xv * H[126 + a];
                s3 += xv * H[189 + a];
            }
            const int d4 = 4 * (s - u);              // -28..32
            {
                int j = d4 + 31;                     // p=0 (j can be 63)
                if (j <= 62) c0 = s0 * G[j] + s1 * G[63 + j] + s2 * G[126 + j] + s3 * G[189 + j];
            }
            {
                int j = d4 + 30;
                c1 = s0 * G[j] + s1 * G[63 + j] + s2 * G[126 + j] + s3 * G[189 + j];
            }
            {
                int j = d4 + 29;
                c2 = s0 * G[j] + s1 * G[63 + j] + s2 * G[126 + j] + s3 * G[189 + j];
            }
            {
                int j = d4 + 28;
                c3 = s0 * G[j] + s1 * G[63 + j] + s2 * G[126 + j] + s3 * G[189 + j];
            }
        }
#pragma unroll
        for (int m = 8; m >= 1; m >>= 1) {
            c0 += __shfl_xor(c0, m);
            c1 += __shfl_xor(c1, m);
            c2 += __shfl_xor(c2, m);
            c3 += __shfl_xor(c3, m);
        }
        if (s_idx == 0) {
            float4 v = make_float4(4.f * c0, 4.f * c1, 4.f * c2, 4.f * c3);
            ob4[u] = v;
        }
    }
}

// ---------------------------------------------------------------------------
// Persistent double-buffered fused PQMF. 64 blocks/batch x 128 threads; block
// bx handles tiles bx and bx+64. Tile B's global loads are ISSUED right after
// the first barrier so their latency hides under tile A's compute (T14
// issue-early/write-late; placed after the barrier because the compiler
// drains vmcnt(0) at barriers). Edges from still-intact buffers at the end.
// ---------------------------------------------------------------------------
__global__ __launch_bounds__(NTHR) void pqmf_fused(const float* __restrict__ x,
                                                   const float* __restrict__ Wg,
                                                   const float* __restrict__ H,
                                                   const float* __restrict__ G,
                                                   float* __restrict__ out) {
    __shared__ float4 xs4[2][LDSQ];

    const int tid = threadIdx.x;
    const int bx = blockIdx.x;           // 0..63
    const int b = blockIdx.y;
    const int Q0a = bx * QPB;            // tile A
    const int Q0b = (bx + 64) * QPB;     // tile B
    const float4* X4 = reinterpret_cast<const float4*>(x + (size_t)b * TT);
    const float4* W4 = reinterpret_cast<const float4*>(Wg);
    float4* ob4 = reinterpret_cast<float4*>(out + (size_t)b * TT);
    const float4 z = make_float4(0.f, 0.f, 0.f, 0.f);

    // ---- stage tile A into buf0 ----
    {
        const int gq0 = Q0a - 16;
#pragma unroll
        for (int it = 0; it < 5; ++it) {
            int j = tid + it * NTHR;
            if (j < TILEQ) {
                int gq = gq0 + j;
                xs4[0][PX(j)] = ((unsigned)gq < (unsigned)SS) ? X4[gq] : z;
            }
        }
    }
    __syncthreads();

    // ---- issue tile B global loads (land during compute A) ----
    const int gq0b = Q0b - 16;
    float4 r0, r1, r2, r3, r4;
    {
        int g0 = gq0b + tid;
        int g1 = g0 + NTHR, g2 = g0 + 2 * NTHR, g3 = g0 + 3 * NTHR, g4 = g0 + 4 * NTHR;
        r0 = ((unsigned)g0 < (unsigned)SS) ? X4[g0] : z;
        r1 = ((unsigned)g1 < (unsigned)SS) ? X4[g1] : z;
        r2 = ((unsigned)g2 < (unsigned)SS) ? X4[g2] : z;
        r3 = ((unsigned)g3 < (unsigned)SS) ? X4[g3] : z;
        r4 = (tid < TILEQ - 4 * NTHR && (unsigned)g4 < (unsigned)SS) ? X4[g4] : z;
    }

    // ---- compute + store tile A ----
    compute_tile(xs4[0], W4, ob4, Q0a, tid);

    // ---- write tile B to buf1 (vmcnt wait inserted here), barrier ----
    xs4[1][PX(tid)]            = r0;
    xs4[1][PX(tid + NTHR)]     = r1;
    xs4[1][PX(tid + 2 * NTHR)] = r2;
    xs4[1][PX(tid + 3 * NTHR)] = r3;
    if (tid < TILEQ - 4 * NTHR) xs4[1][PX(tid + 4 * NTHR)] = r4;
    __syncthreads();

    // ---- compute + store tile B ----
    compute_tile(xs4[1], W4, ob4, Q0b, tid);

    // ---- edges: buf0 (tile 0) and buf1 (tile 127) are still intact ----
    if (bx == 0)
        edge16(reinterpret_cast<const float*>(xs4[0]), Q0a, H, G, ob4, 0, tid);
    if (bx == 63)
        edge16(reinterpret_cast<const float*>(xs4[1]), Q0b, H, G, ob4, SS - 16, tid);
}

extern "C" void kernel_launch(void* const* d_in, const int* in_sizes, int n_in,
                              void* d_out, int out_size, void* d_ws, size_t ws_size,
                              hipStream_t stream) {
    const float* x = (const float*)d_in[0];
    const float* H = (const float*)d_in[1];
    const float* G = (const float*)d_in[2];
    float* outp = (float*)d_out;
    float* W = (float*)d_ws;   // 4*132 floats = 2112 B

    hipLaunchKernelGGL(prep_w, dim3(9), dim3(256), 0, stream, H, G, W);
    hipLaunchKernelGGL(pqmf_fused, dim3(64, BB), dim3(NTHR), 0, stream,
                       x, W, H, G, outp);
}